// Round 17
// baseline (1749.483 us; speedup 1.0000x reference)
//
#include <hip/hip_runtime.h>
#include <hip/hip_bf16.h>
#include <stdint.h>

// out[b,o] = sum_i x[b,i]*(bw[o,i] + dwb[o,i] + T[b,i]) + bbias[o] + dbb[o] + dot(z[b,:], dbW[o,:])
//   where T[b,i] = sum_k z[b,k] * dwW[o*IN + i, k]
//
// One block per output column o; streams the contiguous 512 KB dwW slab once.
//
// r11: WRITE 1.68GB => register spills (live ~190 > 128 cap). 982 us.
// r12: slim accumulators (pt[8] scalar), 1-deep prefetch => no spills,
//      kernel ~250 us (below fill kernels in rocprof top-5). ~2.1 TB/s.
// r13 theory: residual 3x vs 6.4 TB/s floor is pipeline DEPTH: 1-deep
//      prefetch alternates issue/drain (~1 tile = 8 KB outstanding/wave).
//      Restore r11's 2-deep named double-buffer at the slim footprint
//      (live ~132 VGPR) with launch_bounds(256,3) (VGPR cap ~170, 12
//      waves/CU, 3 blocks/CU): loads for t+2 issue before the t+1 wait.
// HBM floor = 512 MB / 6.3 TB/s ~ 83 us -> memory-bound.

#define IN_N  1024
#define OUT_N 1024
#define ZD_N  128
#define B_N   128

typedef __attribute__((ext_vector_type(8))) short s16x8;  // 8 bf16 (4 VGPRs)
typedef __attribute__((ext_vector_type(4))) float f32x4;

__global__ __launch_bounds__(256, 3) void hyper_fused(
    const float* __restrict__ x,     // [128,1024]
    const float* __restrict__ z,     // [128,128]
    const float* __restrict__ bw,    // [1024,1024]
    const float* __restrict__ dwW,   // [1024*1024,128] row-major, K contiguous
    const float* __restrict__ dwb,   // [1024*1024] viewed as [1024,1024]
    const float* __restrict__ bbias, // [1024]
    const float* __restrict__ dbW,   // [1024,128]
    const float* __restrict__ dbb,   // [1024]
    float* __restrict__ out)         // [128,1024]
{
    __shared__ s16x8 zlds[16 * 128];  // [k-granule g = k/8][b], bf16, 32 KB
    __shared__ float wlds[IN_N];      // bw[o,:] + dwb[o,:], fp32, 4 KB
    __shared__ float red[4][B_N];     // per-wave partial sums over i

    const int tid  = threadIdx.x;
    const int lane = tid & 63;
    const int w    = tid >> 6;   // wave 0..3
    const int q    = lane >> 4;
    const int l16  = lane & 15;
    const int o    = blockIdx.x;

    // ---- stage z -> LDS bf16, [g][b] layout (conflict-free ds_read_b128)
    {
        const int m  = tid & 127;
        const int g0 = (tid >> 7) * 8;  // this thread's 8 granules
        const float* zr = z + (size_t)m * ZD_N + g0 * 8;
#pragma unroll
        for (int j = 0; j < 8; ++j) {
            float4 a = *(const float4*)(zr + j * 8);
            float4 b = *(const float4*)(zr + j * 8 + 4);
            union { s16x8 v; __hip_bfloat162 b2[4]; } u;
            u.b2[0] = __float22bfloat162_rn(make_float2(a.x, a.y));
            u.b2[1] = __float22bfloat162_rn(make_float2(a.z, a.w));
            u.b2[2] = __float22bfloat162_rn(make_float2(b.x, b.y));
            u.b2[3] = __float22bfloat162_rn(make_float2(b.z, b.w));
            zlds[(g0 + j) * 128 + m] = u.v;
        }
    }
    // ---- stage wsum = bw[o,:] + dwb[o,:] -> LDS fp32 (coalesced float4)
    {
        float4 a = *(const float4*)(bw  + (size_t)o * IN_N + tid * 4);
        float4 b = *(const float4*)(dwb + (size_t)o * IN_N + tid * 4);
        *(float4*)&wlds[tid * 4] =
            make_float4(a.x + b.x, a.y + b.y, a.z + b.z, a.w + b.w);
    }
    __syncthreads();

    // ---- main loop: wave w owns i in [w*256, (w+1)*256), 16 tiles of 16 i.
    // Per tile the wave sweeps a contiguous aligned 8 KB block of dwW, once.
    const int ibase = w * 256;
    const float* lp = dwW + (size_t)o * IN_N * ZD_N + (size_t)(ibase + l16) * ZD_N + q * 8;

    float pt[8];      // [bt]: partial over i for b = bt*16 + l16
#pragma unroll
    for (int bt = 0; bt < 8; ++bt) pt[bt] = 0.f;

    // Two named prefetch buffers (static indexing only -- rule #20): loads
    // for tile t+2 are issued while tile t computes => 2 tiles (16 KB/wave)
    // of stream latency cover, issue overlapped with drain.
    f32x4 bregA[8], bregB[8];
#define LOADI(DST, IT)                                                          \
    {                                                                           \
        const float* p_ = lp + (size_t)(IT) * (16 * ZD_N);                      \
        _Pragma("unroll") for (int s = 0; s < 4; ++s) {                         \
            DST[s * 2 + 0] =                                                    \
                __builtin_nontemporal_load((const f32x4*)(p_ + s * 32));        \
            DST[s * 2 + 1] =                                                    \
                __builtin_nontemporal_load((const f32x4*)(p_ + s * 32 + 4));    \
        }                                                                       \
    }

#define STEP(BUF, IT, PF)                                                       \
    {                                                                           \
        s16x8 bfr[4];                                                           \
        _Pragma("unroll") for (int s = 0; s < 4; ++s) {                         \
            union { s16x8 v; __hip_bfloat162 b2[4]; } u;                        \
            u.b2[0] = __float22bfloat162_rn(                                    \
                make_float2(BUF[s * 2][0], BUF[s * 2][1]));                     \
            u.b2[1] = __float22bfloat162_rn(                                    \
                make_float2(BUF[s * 2][2], BUF[s * 2][3]));                     \
            u.b2[2] = __float22bfloat162_rn(                                    \
                make_float2(BUF[s * 2 + 1][0], BUF[s * 2 + 1][1]));             \
            u.b2[3] = __float22bfloat162_rn(                                    \
                make_float2(BUF[s * 2 + 1][2], BUF[s * 2 + 1][3]));             \
            bfr[s] = u.v;                                                       \
        }                                                                       \
        if (PF) LOADI(BUF, (IT) + 2);   /* overwrite only after cvt consumed */ \
        const int i0 = ibase + (IT) * 16 + q * 4;  /* this lane's C/D rows   */ \
        const float4 wsv = *(const float4*)&wlds[i0];                           \
        f32x4 acc[8];                                                           \
        _Pragma("unroll") for (int bt = 0; bt < 8; ++bt) acc[bt] = (f32x4)0.0f; \
        _Pragma("unroll") for (int s = 0; s < 4; ++s) {                         \
            const s16x8* zp = &zlds[(s * 4 + q) * 128 + l16];                   \
            _Pragma("unroll") for (int bt = 0; bt < 8; ++bt)                    \
                acc[bt] = __builtin_amdgcn_mfma_f32_16x16x32_bf16(              \
                    bfr[s], zp[bt * 16], acc[bt], 0, 0, 0);                     \
        }                                                                       \
        /* C/D: col = l16 (= b, +bt*16), row = q*4 + r (= i_local).          */ \
        /* fp32 fold + in-tile r-sum: pt[bt] += sum_r (T+w)[r]*x[b][i0+r]    */ \
        _Pragma("unroll") for (int bt = 0; bt < 8; ++bt) {                      \
            const float4 xv =                                                   \
                *(const float4*)(x + (size_t)(bt * 16 + l16) * IN_N + i0);      \
            pt[bt] += (acc[bt][0] + wsv.x) * xv.x                               \
                    + (acc[bt][1] + wsv.y) * xv.y                               \
                    + (acc[bt][2] + wsv.z) * xv.z                               \
                    + (acc[bt][3] + wsv.w) * xv.w;                              \
        }                                                                       \
    }

    LOADI(bregA, 0);
    LOADI(bregB, 1);
#pragma unroll
    for (int it2 = 0; it2 < 8; ++it2) {
        STEP(bregA, it2 * 2,     it2 < 7);
        STEP(bregB, it2 * 2 + 1, it2 < 7);
    }
#undef STEP
#undef LOADI

    // ---- reduce over i: across q-groups (i-partition is exact)
#pragma unroll
    for (int bt = 0; bt < 8; ++bt) {
        float s = pt[bt];
        s += __shfl_xor(s, 16, 64);
        s += __shfl_xor(s, 32, 64);
        if (lane < 16) red[w][bt * 16 + l16] = s;
    }
    __syncthreads();

    // ---- cross-wave combine + small terms (fp32 exact), one thread per b
    if (tid < B_N) {
        const int b = tid;
        float s = red[0][b] + red[1][b] + red[2][b] + red[3][b]
                + bbias[o] + dbb[o];
        const float* zr = z + (size_t)b * ZD_N;
        const float* dr = dbW + (size_t)o * ZD_N;
#pragma unroll 8
        for (int k = 0; k < ZD_N; k += 4) {
            float4 zv = *(const float4*)(zr + k);
            float4 dv = *(const float4*)(dr + k);
            s += zv.x * dv.x + zv.y * dv.y + zv.z * dv.z + zv.w * dv.w;
        }
        out[(size_t)b * OUT_N + o] = s;
    }
}

extern "C" void kernel_launch(void* const* d_in, const int* in_sizes, int n_in,
                              void* d_out, int out_size, void* d_ws, size_t ws_size,
                              hipStream_t stream) {
    hipLaunchKernelGGL(hyper_fused, dim3(OUT_N), dim3(256), 0, stream,
                       (const float*)d_in[0],  // x
                       (const float*)d_in[1],  // z
                       (const float*)d_in[2],  // base_weight
                       (const float*)d_in[3],  // dw_W
                       (const float*)d_in[4],  // dw_b
                       (const float*)d_in[5],  // base_bias
                       (const float*)d_in[6],  // db_W
                       (const float*)d_in[7],  // db_b
                       (float*)d_out);
}